// Round 3
// baseline (282.299 us; speedup 1.0000x reference)
//
#include <hip/hip_runtime.h>

namespace {

constexpr int kB = 4096;
constexpr int kT = 256;
constexpr int kLags = 32;
constexpr int kH = 128;
constexpr int kSteps = 255;   // 32 warmup + 223 AR steps
constexpr int kOut = 224;     // kT - kLags
constexpr int kMT = 16;       // batch rows per block
constexpr int kThreads = 512; // 8 waves: 0-3 = H-role (a1,a2,tanh), 4-7 = L-role (a3,pred)
constexpr int kHS = 136;      // bf16 row stride: 272 B (measured-benign banks)
constexpr int kOS = 225;      // obuf row stride
constexpr int kHLO = 2 * kMT * kHS;  // shorts: constant offset hhi[p][n] -> hlo[p][n]
constexpr int kAS = 20;       // abuf row stride (shorts): 8B-aligned slots, spreads banks

// z-path pre-scale: 2 * log2(e). tanh(z) = 1 - 2/(exp2(2*log2e*z)+1).
constexpr float kZS = 2.8853900817779268f;

typedef __attribute__((ext_vector_type(8))) short short8;
typedef __attribute__((ext_vector_type(4))) float f32x4;

struct __align__(16) SMem {
    unsigned short hhi[2][kMT][kHS];  // h high bf16, [buf][batch][col]
    unsigned short hlo[2][kMT][kHS];  // h low  bf16 (MUST follow hhi: kHLO offset trick)
    float x0T[kT][kMT];               // feature 0, transposed [t][batch]
    float x1wT[kLags][kMT];           // feature 1 warmup, transposed
    unsigned short abuf[8][kMT][kAS]; // a3 = W_hi*h_lo correction, bf16, [tile][n][4q+r]
    float pbuf[2][4][kMT];            // per-wave Wd-partial staging (double-buffered)
    float obuf[kMT][kOS];             // ES output staging
};

__device__ __forceinline__ unsigned short bf16_rne(float f) {
    unsigned u = __builtin_bit_cast(unsigned, f);
    u += 0x7FFFu + ((u >> 16) & 1u);
    return (unsigned short)(u >> 16);
}
__device__ __forceinline__ float bf16_f32(unsigned short h) {
    unsigned u = ((unsigned)h) << 16;
    return __builtin_bit_cast(float, u);
}
// tanh(z) given zs = 2*log2(e)*z  (scale folded into weights, exact math)
__device__ __forceinline__ float tanh_from_zs(float zs) {
    float e = __builtin_amdgcn_exp2f(zs);
    return fmaf(-2.0f, __builtin_amdgcn_rcpf(e + 1.0f), 1.0f);
}
// RNE bf16 in TOP 16 bits (for v_perm byte [7,6]/[3,2] extraction)
__device__ __forceinline__ unsigned bf16_rne_hibits(float f) {
    unsigned u = __builtin_bit_cast(unsigned, f);
    return (u + (0x7FFFu + ((u >> 16) & 1u))) & 0xFFFF0000u;
}

__global__ __launch_bounds__(kThreads, 2)
void arx_rnn_es_kernel(const float* __restrict__ inputs,
                       const float* __restrict__ Wx,
                       const float* __restrict__ Wh,
                       const float* __restrict__ bias,
                       const float* __restrict__ Wd,
                       const float* __restrict__ bd,
                       const float* __restrict__ alpha,
                       float* __restrict__ out) {
    __shared__ SMem sm;
    const int tid  = threadIdx.x;
    const int b0   = blockIdx.x * kMT;
    const int lane = tid & 63;
    const int w    = tid >> 6;        // wave 0..7
    const int v    = w & 3;           // tile-group: tiles 2v, 2v+1 (cols 32v..32v+31)
    const bool hrole = (w < 4);       // H-role: a1,a2 + tanh + h-write; L-role: a3 + pred/ES
    const int n    = lane & 15;       // batch row (B-frag col & C col)
    const int q    = lane >> 4;       // quad: C rows 4q..4q+3 (= outcols in tile)

    // ---------------- one-time staging ----------------
    for (int idx = tid; idx < kMT * kT; idx += kThreads) {
        const int mm = idx >> 8;
        const int t  = idx & 255;
        float2 val = ((const float2*)inputs)[(size_t)(b0 + mm) * kT + t];
        sm.x0T[t][mm] = val.x;
        if (t < kLags) sm.x1wT[t][mm] = val.y;
    }
    for (int idx = tid; idx < kMT * kHS; idx += kThreads) {
        ((unsigned short*)sm.hhi[0])[idx] = 0;
        ((unsigned short*)sm.hlo[0])[idx] = 0;
    }

    const float av  = fminf(fmaxf(alpha[0], 0.0f), 1.0f);
    const float bdv = bd[0];

    // ---- epilogue constants per tile (H-role only; all z-path consts kZS-scaled) ----
    f32x4 sb2v[2], swx0v[2], swx1ev[2], sbpv[2];
    if (hrole) {
#pragma unroll
        for (int t = 0; t < 2; ++t) {
#pragma unroll
            for (int r = 0; r < 4; ++r) {
                const int colE = v * 32 + t * 16 + q * 4 + r;
                const float bc = bias[colE];
                const float w0 = Wx[colE];
                const float w1 = Wx[kH + colE];
                sb2v[t][r]   = kZS * bc;
                swx0v[t][r]  = kZS * w0;
                swx1ev[t][r] = kZS * w1;
                sbpv[t][r]   = kZS * (bc + bdv * w1);   // folded bias for AR steps
            }
        }
    }
    __syncthreads();

    const f32x4 zero4 = {0.0f, 0.0f, 0.0f, 0.0f};
    int p = 0;

    // ================= warmup: st = 0..31 (unfolded kZS*Wh, real x1) ===============
    {
        // H-role: whh + whl for tiles 2v,2v+1. L-role: whh only (a3 = whh * h_lo).
        short8 wHi[2][4], wLo[2][4];
#pragma unroll
        for (int t = 0; t < 2; ++t) {
            const int colw = v * 32 + t * 16 + n;
#pragma unroll
            for (int c = 0; c < 4; ++c) {
#pragma unroll
                for (int j = 0; j < 8; ++j) {
                    const int k = c * 32 + q * 8 + j;
                    float wv = kZS * Wh[(size_t)k * kH + colw];
                    unsigned short hi = bf16_rne(wv);
                    wHi[t][c][j] = (short)hi;
                    if (hrole) wLo[t][c][j] = (short)bf16_rne(wv - bf16_f32(hi));
                }
            }
        }

#pragma unroll 1
        for (int st = 0; st < kLags; ++st) {
            f32x4 A1[2], A2[2], A3[2];
            if (hrole) {
                const float x0s = sm.x0T[st][n];
                const float x1s = sm.x1wT[st][n];
                const unsigned short* hb = (const unsigned short*)&sm.hhi[p][n][0];
                short8 bh[4];
#pragma unroll
                for (int c = 0; c < 4; ++c)
                    bh[c] = *(const short8*)(hb + c * 32 + 8 * q);
#pragma unroll
                for (int t = 0; t < 2; ++t) {
                    f32x4 xi;
#pragma unroll
                    for (int r = 0; r < 4; ++r)
                        xi[r] = fmaf(x0s, swx0v[t][r], x1s * swx1ev[t][r]);
                    A1[t] = __builtin_amdgcn_mfma_f32_16x16x32_bf16(wHi[t][0], bh[0], sb2v[t], 0, 0, 0);
                    A2[t] = __builtin_amdgcn_mfma_f32_16x16x32_bf16(wLo[t][0], bh[0], xi,      0, 0, 0);
#pragma unroll
                    for (int c = 1; c < 4; ++c) {
                        A1[t] = __builtin_amdgcn_mfma_f32_16x16x32_bf16(wHi[t][c], bh[c], A1[t], 0, 0, 0);
                        A2[t] = __builtin_amdgcn_mfma_f32_16x16x32_bf16(wLo[t][c], bh[c], A2[t], 0, 0, 0);
                    }
                }
            } else {
                const unsigned short* hb = (const unsigned short*)&sm.hhi[p][n][0];
                short8 bl[4];
#pragma unroll
                for (int c = 0; c < 4; ++c)
                    bl[c] = *(const short8*)(hb + kHLO + c * 32 + 8 * q);
#pragma unroll
                for (int t = 0; t < 2; ++t) {
                    A3[t] = __builtin_amdgcn_mfma_f32_16x16x32_bf16(wHi[t][0], bl[0], zero4, 0, 0, 0);
#pragma unroll
                    for (int c = 1; c < 4; ++c)
                        A3[t] = __builtin_amdgcn_mfma_f32_16x16x32_bf16(wHi[t][c], bl[c], A3[t], 0, 0, 0);
                    // pack a3 correction to bf16 (O(2^-8) term; quantization ~1e-5)
                    unsigned rb0 = bf16_rne_hibits(A3[t][0]);
                    unsigned rb1 = bf16_rne_hibits(A3[t][1]);
                    unsigned rb2 = bf16_rne_hibits(A3[t][2]);
                    unsigned rb3 = bf16_rne_hibits(A3[t][3]);
                    uint2 ua;
                    ua.x = __builtin_amdgcn_perm(rb1, rb0, 0x07060302u);
                    ua.y = __builtin_amdgcn_perm(rb3, rb2, 0x07060302u);
                    *(uint2*)&sm.abuf[2 * v + t][n][4 * q] = ua;
                }
            }
            __syncthreads();   // barrier-1: a3 partials visible

            if (hrole) {
                unsigned short* hw = (unsigned short*)&sm.hhi[p ^ 1][n][0];
#pragma unroll
                for (int t = 0; t < 2; ++t) {
                    uint2 a3p = *(const uint2*)&sm.abuf[2 * v + t][n][4 * q];
                    float a3f[4];
                    a3f[0] = __builtin_bit_cast(float, a3p.x << 16);
                    a3f[1] = __builtin_bit_cast(float, a3p.x & 0xFFFF0000u);
                    a3f[2] = __builtin_bit_cast(float, a3p.y << 16);
                    a3f[3] = __builtin_bit_cast(float, a3p.y & 0xFFFF0000u);
                    unsigned rb[4], db[4];
#pragma unroll
                    for (int r = 0; r < 4; ++r) {
                        float zs = (A1[t][r] + A2[t][r]) + a3f[r];
                        float hf = tanh_from_zs(zs);
                        rb[r] = bf16_rne_hibits(hf);
                        float d = hf - __builtin_bit_cast(float, rb[r]);
                        db[r] = __builtin_bit_cast(unsigned, d);   // trunc lo (top 16 bits)
                    }
                    uint2 uh, ul;
                    uh.x = __builtin_amdgcn_perm(rb[1], rb[0], 0x07060302u);
                    uh.y = __builtin_amdgcn_perm(rb[3], rb[2], 0x07060302u);
                    ul.x = __builtin_amdgcn_perm(db[1], db[0], 0x07060302u);
                    ul.y = __builtin_amdgcn_perm(db[3], db[2], 0x07060302u);
                    const int wcol = v * 32 + t * 16 + q * 4;
                    *(uint2*)(hw + wcol) = uh;
                    *(uint2*)(hw + kHLO + wcol) = ul;
                }
            }
            __syncthreads();   // barrier-2: new h complete
            p ^= 1;
        }
    }

    // ---- AR weights: folded kZS*(Wh + Wd*wx1^T). H-role: hi+lo; L-role: hi + Wd slice ----
    short8 fHi[2][4], fLo[2][4], dhv;
    {
#pragma unroll
        for (int t = 0; t < 2; ++t) {
            const int colw = v * 32 + t * 16 + n;
            const float wx1w = Wx[kH + colw];
#pragma unroll
            for (int c = 0; c < 4; ++c) {
#pragma unroll
                for (int j = 0; j < 8; ++j) {
                    const int k = c * 32 + q * 8 + j;
                    float wv = kZS * fmaf(Wd[k], wx1w, Wh[(size_t)k * kH + colw]);
                    unsigned short hi = bf16_rne(wv);
                    fHi[t][c][j] = (short)hi;
                    if (hrole) fLo[t][c][j] = (short)bf16_rne(wv - bf16_f32(hi));
                }
            }
        }
        if (!hrole) {
#pragma unroll
            for (int j = 0; j < 8; ++j)
                dhv[j] = (short)bf16_rne(Wd[v * 32 + q * 8 + j]);  // pred k-slice v
        }
    }

    float es = 0.0f;   // wave 4, q==0 lanes: es for batch row n

    // ========= AR: st = 32..254. Phase-A: H-role a1,a2 (16 MFMA) / L-role a3 (8 MFMA)+pack.
    // ========= Phase-B: H-role a3-sum+tanh+h-write / L-role pred MFMA + deferred ES.
#pragma unroll 1
    for (int st = kLags; st < kSteps; ++st) {
        f32x4 A1[2], A2[2];
        if (hrole) {
            const float x0s = sm.x0T[st][n];
            const unsigned short* hb = (const unsigned short*)&sm.hhi[p][n][0];
            short8 bh[4];
#pragma unroll
            for (int c = 0; c < 4; ++c)
                bh[c] = *(const short8*)(hb + c * 32 + 8 * q);
#pragma unroll
            for (int t = 0; t < 2; ++t) {
                f32x4 xi;
#pragma unroll
                for (int r = 0; r < 4; ++r) xi[r] = x0s * swx0v[t][r];
                A1[t] = __builtin_amdgcn_mfma_f32_16x16x32_bf16(fHi[t][0], bh[0], sbpv[t], 0, 0, 0);
                A2[t] = __builtin_amdgcn_mfma_f32_16x16x32_bf16(fLo[t][0], bh[0], xi,      0, 0, 0);
#pragma unroll
                for (int c = 1; c < 4; ++c) {
                    A1[t] = __builtin_amdgcn_mfma_f32_16x16x32_bf16(fHi[t][c], bh[c], A1[t], 0, 0, 0);
                    A2[t] = __builtin_amdgcn_mfma_f32_16x16x32_bf16(fLo[t][c], bh[c], A2[t], 0, 0, 0);
                }
            }
        } else {
            const unsigned short* hb = (const unsigned short*)&sm.hhi[p][n][0];
            short8 bl[4];
#pragma unroll
            for (int c = 0; c < 4; ++c)
                bl[c] = *(const short8*)(hb + kHLO + c * 32 + 8 * q);
#pragma unroll
            for (int t = 0; t < 2; ++t) {
                f32x4 A3 = __builtin_amdgcn_mfma_f32_16x16x32_bf16(fHi[t][0], bl[0], zero4, 0, 0, 0);
#pragma unroll
                for (int c = 1; c < 4; ++c)
                    A3 = __builtin_amdgcn_mfma_f32_16x16x32_bf16(fHi[t][c], bl[c], A3, 0, 0, 0);
                unsigned rb0 = bf16_rne_hibits(A3[0]);
                unsigned rb1 = bf16_rne_hibits(A3[1]);
                unsigned rb2 = bf16_rne_hibits(A3[2]);
                unsigned rb3 = bf16_rne_hibits(A3[3]);
                uint2 ua;
                ua.x = __builtin_amdgcn_perm(rb1, rb0, 0x07060302u);
                ua.y = __builtin_amdgcn_perm(rb3, rb2, 0x07060302u);
                *(uint2*)&sm.abuf[2 * v + t][n][4 * q] = ua;
            }
        }
        __syncthreads();   // barrier-1: a3 partials visible

        if (hrole) {
            unsigned short* hw = (unsigned short*)&sm.hhi[p ^ 1][n][0];
#pragma unroll
            for (int t = 0; t < 2; ++t) {
                uint2 a3p = *(const uint2*)&sm.abuf[2 * v + t][n][4 * q];
                float a3f[4];
                a3f[0] = __builtin_bit_cast(float, a3p.x << 16);
                a3f[1] = __builtin_bit_cast(float, a3p.x & 0xFFFF0000u);
                a3f[2] = __builtin_bit_cast(float, a3p.y << 16);
                a3f[3] = __builtin_bit_cast(float, a3p.y & 0xFFFF0000u);
                unsigned rb[4], db[4];
#pragma unroll
                for (int r = 0; r < 4; ++r) {
                    float zs = (A1[t][r] + A2[t][r]) + a3f[r];
                    float hf = tanh_from_zs(zs);
                    rb[r] = bf16_rne_hibits(hf);
                    float d = hf - __builtin_bit_cast(float, rb[r]);
                    db[r] = __builtin_bit_cast(unsigned, d);
                }
                uint2 uh, ul;
                uh.x = __builtin_amdgcn_perm(rb[1], rb[0], 0x07060302u);
                uh.y = __builtin_amdgcn_perm(rb[3], rb[2], 0x07060302u);
                ul.x = __builtin_amdgcn_perm(db[1], db[0], 0x07060302u);
                ul.y = __builtin_amdgcn_perm(db[3], db[2], 0x07060302u);
                const int wcol = v * 32 + t * 16 + q * 4;
                *(uint2*)(hw + wcol) = uh;
                *(uint2*)(hw + kHLO + wcol) = ul;
            }
        } else {
            // pred partial for k-slice v from h_hi[p] (h_lo term ~3e-4, ES-smoothed)
            const unsigned short* hb = (const unsigned short*)&sm.hhi[p][n][0];
            short8 bhP = *(const short8*)(hb + v * 32 + 8 * q);
            f32x4 P = __builtin_amdgcn_mfma_f32_16x16x32_bf16(dhv, bhP, zero4, 0, 0, 0);
            if (q == 0) sm.pbuf[p][v][n] = P[0];

            // deferred ES: finish pred of step st-1 from last step's partials
            if (w == 4 && q == 0 && st > kLags) {
                float pv = ((sm.pbuf[p ^ 1][0][n] + sm.pbuf[p ^ 1][1][n]) +
                            (sm.pbuf[p ^ 1][2][n] + sm.pbuf[p ^ 1][3][n])) + bdv;
                const int m = st - kLags - 1;
                es = (m == 0) ? pv : fmaf(av, pv - es, es);
                sm.obuf[n][m] = es;
            }
        }
        __syncthreads();   // barrier-2: new h complete, pbuf written
        p ^= 1;
    }

    // ===== tail: finish pred_222 (pbuf[p^1]), then pred_223 from h_255 =====
    if (w == 4 && q == 0) {
        float pv = ((sm.pbuf[p ^ 1][0][n] + sm.pbuf[p ^ 1][1][n]) +
                    (sm.pbuf[p ^ 1][2][n] + sm.pbuf[p ^ 1][3][n])) + bdv;
        es = fmaf(av, pv - es, es);
        sm.obuf[n][kOut - 2] = es;
    }
    if (!hrole) {
        const unsigned short* hb = (const unsigned short*)&sm.hhi[p][n][0];
        short8 bhP = *(const short8*)(hb + v * 32 + 8 * q);
        f32x4 P = __builtin_amdgcn_mfma_f32_16x16x32_bf16(dhv, bhP, zero4, 0, 0, 0);
        if (q == 0) sm.pbuf[p][v][n] = P[0];
    }
    __syncthreads();
    if (w == 4 && q == 0) {
        float pv = ((sm.pbuf[p][0][n] + sm.pbuf[p][1][n]) +
                    (sm.pbuf[p][2][n] + sm.pbuf[p][3][n])) + bdv;
        es = fmaf(av, pv - es, es);
        sm.obuf[n][kOut - 1] = es;
    }

    // ================= flush ES staging buffer to HBM (coalesced) =================
    __syncthreads();
    for (int idx = tid; idx < kMT * kOut; idx += kThreads) {
        const int mm = idx / kOut;
        const int t  = idx - mm * kOut;
        out[(size_t)(b0 + mm) * kOut + t] = sm.obuf[mm][t];
    }
}

}  // namespace

extern "C" void kernel_launch(void* const* d_in, const int* in_sizes, int n_in,
                              void* d_out, int out_size, void* d_ws, size_t ws_size,
                              hipStream_t stream) {
    const float* inputs = (const float*)d_in[0];
    const float* Wx     = (const float*)d_in[1];
    const float* Wh     = (const float*)d_in[2];
    const float* bias   = (const float*)d_in[3];
    const float* Wd     = (const float*)d_in[4];
    const float* bd     = (const float*)d_in[5];
    const float* alpha  = (const float*)d_in[6];
    // d_in[7] = lags (compile-time constant 32 here)

    arx_rnn_es_kernel<<<kB / kMT, kThreads, 0, stream>>>(
        inputs, Wx, Wh, bias, Wd, bd, alpha, (float*)d_out);
}